// Round 3
// baseline (788.525 us; speedup 1.0000x reference)
//
#include <hip/hip_runtime.h>
#include <hip/hip_bf16.h>

constexpr int NN = 50000;
constexpr int EE = 200000;
typedef __bf16 bf16x8 __attribute__((ext_vector_type(8)));
typedef float f32x4 __attribute__((ext_vector_type(4)));

__device__ __forceinline__ float b2f(unsigned short s) {
    union { unsigned u; float f; } c; c.u = ((unsigned)s) << 16; return c.f;
}
__device__ __forceinline__ unsigned short f2b(float f) {
    union { float f; unsigned u; } c; c.f = f;
    unsigned u = c.u + 0x7fffu + ((c.u >> 16) & 1u);
    return (unsigned short)(u >> 16);
}
__device__ __forceinline__ float xv(const void* p, long i, int f32m) {
    return f32m ? ((const float*)p)[i] : b2f(((const unsigned short*)p)[i]);
}
__device__ __forceinline__ int iv(const int* p, int i, int i64m) {
    return i64m ? p[2 * i] : p[i];
}

__global__ void k_detect(const unsigned short* x16, const int* c32, int* flg) {
    if (threadIdx.x != 0 || blockIdx.x != 0) return;
    int f32m = 0;
    for (int i = 0; i < 16384; i++)
        if (((x16[i] >> 7) & 0xFF) == 0xFF) { f32m = 1; break; }
    int i64m = 1;
    for (int i = 1; i < 128; i += 2)
        if (c32[i] != 0) { i64m = 0; break; }
    flg[0] = f32m; flg[1] = i64m;
}

__global__ void k_zero(unsigned* p, int n) {
    int i = blockIdx.x * 256 + threadIdx.x;
    if (i < n) p[i] = 0u;
}

// Pack W into bf16 MFMA B-fragment image: chunk=(t*4+c)*64+l ;
// Wf[chunk*8+j] = W[c*32+(l>>4)*8+j][t*16+(l&15)]
__global__ void k_wfrag(const void* W, unsigned short* Wf, const int* flg) {
    int f32m = flg[0];
    int chunk = blockIdx.x * 256 + threadIdx.x;
    if (chunk >= 2048) return;
    int l = chunk & 63, c = (chunk >> 6) & 3, t = chunk >> 8;
    int n = t * 16 + (l & 15), k0 = c * 32 + ((l >> 4) * 8);
    for (int j = 0; j < 8; j++) Wf[chunk * 8 + j] = f2b(xv(W, (long)(k0 + j) * 128 + n, f32m));
}

// ---- CSR build (by col1), done once: counts -> row_ptr/cursor -> elist/aux ----
__global__ void k_hist(const int* col1, int* counts, const int* flg) {
    int e = blockIdx.x * 256 + threadIdx.x;
    if (e >= EE) return;
    atomicAdd(&counts[iv(col1, e, flg[1])], 1);
}

// single-block exclusive scan of counts[0..NN) -> row_ptr & cursor; row_ptr[NN]=total
__global__ void k_scan(const int* counts, int* row_ptr, int* cursor) {
    __shared__ int part[1024];
    int t = threadIdx.x;
    const int CH = (NN + 1023) / 1024;
    int base = t * CH;
    int s = 0;
    for (int i = 0; i < CH; i++) { int idx = base + i; if (idx < NN) s += counts[idx]; }
    part[t] = s;
    __syncthreads();
    for (int off = 1; off < 1024; off <<= 1) {
        int v = (t >= off) ? part[t - off] : 0;
        __syncthreads();
        part[t] += v;
        __syncthreads();
    }
    int ex = (t == 0) ? 0 : part[t - 1];
    for (int i = 0; i < CH; i++) {
        int idx = base + i;
        if (idx < NN) { row_ptr[idx] = ex; cursor[idx] = ex; ex += counts[idx]; }
    }
    if (t == 1023) row_ptr[NN] = part[1023];
}

// elist[pos] = edge id | selfloop<<31 ; aux[pos] = col0[e]
__global__ void k_cscatter(const int* col0, const int* col1, int* cursor,
                           unsigned* elist, int* aux, const int* flg) {
    int e = blockIdx.x * 256 + threadIdx.x;
    if (e >= EE) return;
    int i64m = flg[1];
    int a = iv(col0, e, i64m), b = iv(col1, e, i64m);
    int pos = atomicAdd(&cursor[b], 1);
    elist[pos] = (unsigned)e | (a == b ? 0x80000000u : 0u);
    aux[pos] = a;
}

// S[n][k] (bf16) = sum over in-edges e of n (non-self-loop) of relu(msg):
//   mode 1: msg = 0.5*x[aux[p]][k] + 1.5*x[n][k]   (iter-1, lgX0 never materialized)
//   mode 2: msg = lgX[e][k] + x[n][k]              (iter-2)
// 2 nodes per 256-thread block; thread owns column k -> coalesced row gathers.
__global__ void k_gath(const void* x, const unsigned short* lgX,
                       const int* row_ptr, const unsigned* elist, const int* aux,
                       unsigned short* S, const int* flg, int mode) {
    int n = blockIdx.x * 2 + (threadIdx.x >> 7);
    if (n >= NN) return;
    int k = threadIdx.x & 127;
    int f32m = flg[0];
    int lo = row_ptr[n], hi = row_ptr[n + 1];
    float xn = xv(x, (long)n * 128 + k, f32m);
    float acc = 0.0f;
    for (int p = lo; p < hi; p++) {
        unsigned pk = elist[p];
        if (pk & 0x80000000u) continue;     // self-loop edge sends no message
        float v;
        if (mode == 1) {
            int a = aux[p];
            v = 0.5f * xv(x, (long)a * 128 + k, f32m) + 1.5f * xn;
        } else {
            int e = (int)(pk & 0x7fffffffu);
            v = b2f(lgX[(size_t)e * 128 + k]) + xn;
        }
        if (v > 0.0f) acc += v;
    }
    S[(size_t)n * 128 + k] = f2b(acc);
}

// Fused 2-layer MLP over a 128-row edge tile, K=128:
// Out = (relu((A + S[col0]) @ W1 + b1)) @ W2 + b2,  S is bf16.
// initA=1: A-row computed on the fly as 0.5*(x[col0[e]]+x[col1[e]]) (iter 1).
// initA=0: A-row read from lgX.
__global__ void k_fused(const unsigned short* A, const unsigned short* S,
                        const int* col0in, const int* col1in, const void* x,
                        const unsigned short* Wf1, const unsigned short* Wf2,
                        const void* bias1, const void* bias2,
                        unsigned short* Out, const int* flg, int initA) {
    __shared__ unsigned short Al[16384], Bl[16384];
    int f32m = flg[0], i64m = flg[1];
    int tid = threadIdx.x;
    int e0 = blockIdx.x * 128;
    for (int i = 0; i < 8; i++)
        ((uint4*)Bl)[i * 256 + tid] = ((const uint4*)Wf1)[i * 256 + tid];
    for (int i = 0; i < 8; i++) {
        int chunk = i * 256 + tid;
        int l = chunk & 63, c = (chunk >> 6) & 3, r = chunk >> 8;
        int m = r * 16 + (l & 15), k0 = c * 32 + ((l >> 4) * 8);
        int e = e0 + m;
        unsigned short v[8];
        if (e < EE) {
            int aN = iv(col0in, e, i64m);
            const unsigned short* sp = S + (size_t)aN * 128 + k0;
            if (initA) {
                int bN = iv(col1in, e, i64m);
                for (int j = 0; j < 8; j++) {
                    float lg = 0.5f * (xv(x, (long)aN * 128 + k0 + j, f32m)
                                     + xv(x, (long)bN * 128 + k0 + j, f32m));
                    v[j] = f2b(lg + b2f(sp[j]));
                }
            } else {
                const unsigned short* ap = A + (size_t)e * 128 + k0;
                for (int j = 0; j < 8; j++) v[j] = f2b(b2f(ap[j]) + b2f(sp[j]));
            }
        } else
            for (int j = 0; j < 8; j++) v[j] = 0;
        for (int j = 0; j < 8; j++) Al[chunk * 8 + j] = v[j];
    }
    __syncthreads();
    int w = tid >> 6, l = tid & 63;
    int rt0 = (w & 1) * 4, ct0 = (w >> 1) * 4;
    int lq = l >> 4, ln = l & 15;
    f32x4 acc[4][4];
    for (int i = 0; i < 4; i++)
        for (int j = 0; j < 4; j++)
            for (int r = 0; r < 4; r++) acc[i][j][r] = 0.0f;
    for (int c = 0; c < 4; c++) {
        bf16x8 af[4], bf[4];
        for (int i = 0; i < 4; i++) af[i] = *(const bf16x8*)(Al + (((rt0 + i) * 4 + c) * 64 + l) * 8);
        for (int j = 0; j < 4; j++) bf[j] = *(const bf16x8*)(Bl + (((ct0 + j) * 4 + c) * 64 + l) * 8);
        for (int i = 0; i < 4; i++)
            for (int j = 0; j < 4; j++)
                acc[i][j] = __builtin_amdgcn_mfma_f32_16x16x32_bf16(af[i], bf[j], acc[i][j], 0, 0, 0);
    }
    __syncthreads();   // all MFMA1 reads of Al/Bl done
    // W2 frags -> Bl; H = relu(C1 + b1) -> Al in A-fragment order:
    for (int i = 0; i < 8; i++)
        ((uint4*)Bl)[i * 256 + tid] = ((const uint4*)Wf2)[i * 256 + tid];
    for (int j = 0; j < 4; j++) {
        int n = (ct0 + j) * 16 + ln;
        float bv = xv(bias1, n, f32m);
        int c = n >> 5, lo = ((n >> 3) & 3) * 16, j2 = n & 7;
        for (int i = 0; i < 4; i++) {
            int r = rt0 + i;
            for (int rg = 0; rg < 4; rg++) {
                float h = acc[i][j][rg] + bv;
                if (h < 0.0f) h = 0.0f;
                Al[((r * 4 + c) * 64 + lo + lq * 4 + rg) * 8 + j2] = f2b(h);
            }
        }
    }
    __syncthreads();
    for (int i = 0; i < 4; i++)
        for (int j = 0; j < 4; j++)
            for (int r = 0; r < 4; r++) acc[i][j][r] = 0.0f;
    for (int c = 0; c < 4; c++) {
        bf16x8 af[4], bf[4];
        for (int i = 0; i < 4; i++) af[i] = *(const bf16x8*)(Al + (((rt0 + i) * 4 + c) * 64 + l) * 8);
        for (int j = 0; j < 4; j++) bf[j] = *(const bf16x8*)(Bl + (((ct0 + j) * 4 + c) * 64 + l) * 8);
        for (int i = 0; i < 4; i++)
            for (int j = 0; j < 4; j++)
                acc[i][j] = __builtin_amdgcn_mfma_f32_16x16x32_bf16(af[i], bf[j], acc[i][j], 0, 0, 0);
    }
    __syncthreads();   // before overwriting Al as row-major C2
    for (int j = 0; j < 4; j++) {
        int n = (ct0 + j) * 16 + ln;
        float bv = xv(bias2, n, f32m);
        for (int i = 0; i < 4; i++) {
            int mb = (rt0 + i) * 16 + lq * 4;
            for (int rg = 0; rg < 4; rg++)
                Al[(mb + rg) * 128 + n] = f2b(acc[i][j][rg] + bv);
        }
    }
    __syncthreads();
    // coalesced store: Al row-major == lgX tile layout
    for (int i = 0; i < 8; i++) {
        int idx = i * 256 + tid;
        if (e0 + (idx >> 4) < EE)
            ((uint4*)Out)[(size_t)e0 * 16 + idx] = ((const uint4*)Al)[idx];
    }
}

// out[n] = x[n] + relu(mean over ALL in-edges of lgX[e]) (0 if deg==0).
// deg comes from row_ptr; no cnt, no atomics.
__global__ void LGNNGINELayer_12463995093126_kernel(
    const void* x, const unsigned short* lgX, const int* row_ptr,
    const unsigned* elist, void* out, const int* flg) {
    int n = blockIdx.x * 2 + (threadIdx.x >> 7);
    if (n >= NN) return;
    int k = threadIdx.x & 127;
    int f32m = flg[0];
    int lo = row_ptr[n], hi = row_ptr[n + 1];
    float acc = 0.0f;
    for (int p = lo; p < hi; p++) {
        int e = (int)(elist[p] & 0x7fffffffu);
        acc += b2f(lgX[(size_t)e * 128 + k]);
    }
    float g = 0.0f;
    if (hi > lo) { g = acc / (float)(hi - lo); if (g < 0.0f) g = 0.0f; }
    float r = xv(x, (long)n * 128 + k, f32m) + g;
    if (f32m) ((float*)out)[(long)n * 128 + k] = r;
    else ((unsigned short*)out)[(long)n * 128 + k] = f2b(r);
}

extern "C" void kernel_launch(void* const* d_in, const int* in_sizes, int n_in,
                              void* d_out, int out_size, void* d_ws, size_t ws_size,
                              hipStream_t stream) {
    (void)in_sizes; (void)n_in; (void)out_size; (void)ws_size;
    const void* x = d_in[0];
    const void* W1 = d_in[1];
    const void* b1 = d_in[2];
    const void* W2 = d_in[3];
    const void* b2 = d_in[4];
    const int* col0 = (const int*)d_in[5];
    const int* col1 = (const int*)d_in[6];

    // ws: lgX bf16 51.2MB | S bf16 12.8MB | row_ptr | cursor | counts | aux | elist | flg | Wf1 | Wf2
    char* p = (char*)d_ws;
    unsigned short* lgX = (unsigned short*)p; p += (size_t)EE * 128 * 2;
    unsigned short* S = (unsigned short*)p;   p += (size_t)NN * 128 * 2;
    int* row_ptr = (int*)p;                   p += (size_t)(NN + 16) * 4;
    int* cursor = (int*)p;                    p += (size_t)NN * 4;
    int* counts = (int*)p;                    p += (size_t)NN * 4;
    int* aux = (int*)p;                       p += (size_t)EE * 4;
    unsigned* elist = (unsigned*)p;           p += (size_t)EE * 4;
    int* flg = (int*)p;                       p += 256;
    unsigned short* Wf1 = (unsigned short*)p; p += 16384 * 2;
    unsigned short* Wf2 = (unsigned short*)p;

    int gB = (EE + 127) / 128;
    int eB = (EE + 255) / 256;
    int nB2 = NN / 2;   // NN even: 2 nodes per 256-thread block

    k_detect<<<1, 64, 0, stream>>>((const unsigned short*)x, col0, flg);
    k_wfrag<<<8, 256, 0, stream>>>(W1, Wf1, flg);
    k_wfrag<<<8, 256, 0, stream>>>(W2, Wf2, flg);

    // CSR by col1 (built once; col1 fixed across iterations)
    k_zero<<<(NN + 255) / 256, 256, 0, stream>>>((unsigned*)counts, NN);
    k_hist<<<eB, 256, 0, stream>>>(col1, counts, flg);
    k_scan<<<1, 1024, 0, stream>>>(counts, row_ptr, cursor);
    k_cscatter<<<eB, 256, 0, stream>>>(col0, col1, cursor, elist, aux, flg);

    // iteration 1: S from x directly (lgX0 never materialized), fused MLP -> lgX1
    k_gath<<<nB2, 256, 0, stream>>>(x, lgX, row_ptr, elist, aux, S, flg, 1);
    k_fused<<<gB, 256, 0, stream>>>(lgX, S, col0, col1, x, Wf1, Wf2, b1, b2,
                                    lgX, flg, 1);
    // iteration 2
    k_gath<<<nB2, 256, 0, stream>>>(x, lgX, row_ptr, elist, aux, S, flg, 2);
    k_fused<<<gB, 256, 0, stream>>>(lgX, S, col0, col1, x, Wf1, Wf2, b1, b2,
                                    lgX, flg, 0);
    // scatter_mean back to nodes (as CSR gather) + residual/relu
    LGNNGINELayer_12463995093126_kernel<<<nB2, 256, 0, stream>>>(
        x, lgX, row_ptr, elist, d_out, flg);
}

// Round 4
// 652.225 us; speedup vs baseline: 1.2090x; 1.2090x over previous
//
#include <hip/hip_runtime.h>
#include <hip/hip_bf16.h>

constexpr int NN = 50000;
constexpr int EE = 200000;
typedef __bf16 bf16x8 __attribute__((ext_vector_type(8)));
typedef float f32x4 __attribute__((ext_vector_type(4)));

__device__ __forceinline__ float b2f(unsigned short s) {
    union { unsigned u; float f; } c; c.u = ((unsigned)s) << 16; return c.f;
}
__device__ __forceinline__ unsigned short f2b(float f) {
    union { float f; unsigned u; } c; c.f = f;
    unsigned u = c.u + 0x7fffu + ((c.u >> 16) & 1u);
    return (unsigned short)(u >> 16);
}
__device__ __forceinline__ float xv(const void* p, long i, int f32m) {
    return f32m ? ((const float*)p)[i] : b2f(((const unsigned short*)p)[i]);
}
__device__ __forceinline__ int iv(const int* p, int i, int i64m) {
    return i64m ? p[2 * i] : p[i];
}

__global__ void k_detect(const unsigned short* x16, const int* c32, int* flg) {
    if (threadIdx.x != 0 || blockIdx.x != 0) return;
    int f32m = 0;
    for (int i = 0; i < 16384; i++)
        if (((x16[i] >> 7) & 0xFF) == 0xFF) { f32m = 1; break; }
    int i64m = 1;
    for (int i = 1; i < 128; i += 2)
        if (c32[i] != 0) { i64m = 0; break; }
    flg[0] = f32m; flg[1] = i64m;
}

__global__ void k_zero(unsigned* p, int n) {
    int i = blockIdx.x * 256 + threadIdx.x;
    if (i < n) p[i] = 0u;
}

// Pack W into bf16 MFMA B-fragment image: chunk=(t*4+c)*64+l ;
// Wf[chunk*8+j] = W[c*32+(l>>4)*8+j][t*16+(l&15)]
__global__ void k_wfrag(const void* W, unsigned short* Wf, const int* flg) {
    int f32m = flg[0];
    int chunk = blockIdx.x * 256 + threadIdx.x;
    if (chunk >= 2048) return;
    int l = chunk & 63, c = (chunk >> 6) & 3, t = chunk >> 8;
    int n = t * 16 + (l & 15), k0 = c * 32 + ((l >> 4) * 8);
    for (int j = 0; j < 8; j++) Wf[chunk * 8 + j] = f2b(xv(W, (long)(k0 + j) * 128 + n, f32m));
}

// ---- CSR build (by col1), done once: counts -> row_ptr/cursor -> elist/aux ----
__global__ void k_hist(const int* col1, int* counts, const int* flg) {
    int e = blockIdx.x * 256 + threadIdx.x;
    if (e >= EE) return;
    atomicAdd(&counts[iv(col1, e, flg[1])], 1);
}

// single-block exclusive scan of counts[0..NN) -> row_ptr & cursor; row_ptr[NN]=total
__global__ void k_scan(const int* counts, int* row_ptr, int* cursor) {
    __shared__ int part[1024];
    int t = threadIdx.x;
    const int CH = (NN + 1023) / 1024;
    int base = t * CH;
    int s = 0;
    for (int i = 0; i < CH; i++) { int idx = base + i; if (idx < NN) s += counts[idx]; }
    part[t] = s;
    __syncthreads();
    for (int off = 1; off < 1024; off <<= 1) {
        int v = (t >= off) ? part[t - off] : 0;
        __syncthreads();
        part[t] += v;
        __syncthreads();
    }
    int ex = (t == 0) ? 0 : part[t - 1];
    for (int i = 0; i < CH; i++) {
        int idx = base + i;
        if (idx < NN) { row_ptr[idx] = ex; cursor[idx] = ex; ex += counts[idx]; }
    }
    if (t == 1023) row_ptr[NN] = part[1023];
}

// elist[pos] = edge id | selfloop<<31 ; aux[pos] = col0[e]
__global__ void k_cscatter(const int* col0, const int* col1, int* cursor,
                           unsigned* elist, int* aux, const int* flg) {
    int e = blockIdx.x * 256 + threadIdx.x;
    if (e >= EE) return;
    int i64m = flg[1];
    int a = iv(col0, e, i64m), b = iv(col1, e, i64m);
    int pos = atomicAdd(&cursor[b], 1);
    elist[pos] = (unsigned)e | (a == b ? 0x80000000u : 0u);
    aux[pos] = a;
}

// S[n][k] (bf16) = sum over in-edges e of n (non-self-loop) of relu(msg):
//   mode 1: msg = 0.5*x[aux[p]][k] + 1.5*x[n][k]   (iter-1, lgX0 never materialized)
//   mode 2: msg = lgX[e][k] + x[n][k]              (iter-2)
// One wave per node, lane owns columns 2l,2l+1 -> paired-bf16 u32 row loads.
__global__ void k_gath(const void* x, const unsigned short* lgX,
                       const int* row_ptr, const unsigned* elist, const int* aux,
                       unsigned short* S, const int* flg, int mode) {
    int n = blockIdx.x * 4 + (threadIdx.x >> 6);
    if (n >= NN) return;
    int l = threadIdx.x & 63, k0 = l * 2;
    int f32m = flg[0];
    int lo = row_ptr[n], hi = row_ptr[n + 1];
    float xn0 = xv(x, (long)n * 128 + k0, f32m);
    float xn1 = xv(x, (long)n * 128 + k0 + 1, f32m);
    float a0 = 0.0f, a1 = 0.0f;
    for (int p = lo; p < hi; p++) {
        unsigned pk = elist[p];
        if (pk & 0x80000000u) continue;     // self-loop edge sends no message
        float v0, v1;
        if (mode == 1) {
            int a = aux[p];
            v0 = 0.5f * xv(x, (long)a * 128 + k0, f32m) + 1.5f * xn0;
            v1 = 0.5f * xv(x, (long)a * 128 + k0 + 1, f32m) + 1.5f * xn1;
        } else {
            int e = (int)(pk & 0x7fffffffu);
            unsigned u = *(const unsigned*)(lgX + (size_t)e * 128 + k0);
            v0 = b2f((unsigned short)u) + xn0;
            v1 = b2f((unsigned short)(u >> 16)) + xn1;
        }
        a0 += fmaxf(v0, 0.0f);
        a1 += fmaxf(v1, 0.0f);
    }
    unsigned o = ((unsigned)f2b(a1) << 16) | (unsigned)f2b(a0);
    *(unsigned*)(S + (size_t)n * 128 + k0) = o;
}

// Fused 2-layer MLP over a 128-row edge tile, K=128:
// Out = (relu((A + S[col0]) @ W1 + b1)) @ W2 + b2,  S is bf16.
// initA=1: A-row computed on the fly as 0.5*(x[col0[e]]+x[col1[e]]) (iter 1).
// B-fragments read straight from global Wf (identical for every block -> L1/L2
// resident); LDS is Al only (32 KB) -> 4-5 blocks/CU instead of 2.
__global__ __launch_bounds__(256, 4)
void k_fused(const unsigned short* A, const unsigned short* S,
             const int* col0in, const int* col1in, const void* x,
             const unsigned short* Wf1, const unsigned short* Wf2,
             const void* bias1, const void* bias2,
             unsigned short* Out, const int* flg, int initA) {
    __shared__ unsigned short Al[16384];
    int f32m = flg[0], i64m = flg[1];
    int tid = threadIdx.x;
    int e0 = blockIdx.x * 128;
    for (int i = 0; i < 8; i++) {
        int chunk = i * 256 + tid;
        int l = chunk & 63, c = (chunk >> 6) & 3, r = chunk >> 8;
        int m = r * 16 + (l & 15), k0 = c * 32 + ((l >> 4) * 8);
        int e = e0 + m;
        unsigned short v[8];
        if (e < EE) {
            int aN = iv(col0in, e, i64m);
            const unsigned short* sp = S + (size_t)aN * 128 + k0;
            if (initA) {
                int bN = iv(col1in, e, i64m);
                for (int j = 0; j < 8; j++) {
                    float lg = 0.5f * (xv(x, (long)aN * 128 + k0 + j, f32m)
                                     + xv(x, (long)bN * 128 + k0 + j, f32m));
                    v[j] = f2b(lg + b2f(sp[j]));
                }
            } else {
                const unsigned short* ap = A + (size_t)e * 128 + k0;
                for (int j = 0; j < 8; j++) v[j] = f2b(b2f(ap[j]) + b2f(sp[j]));
            }
        } else
            for (int j = 0; j < 8; j++) v[j] = 0;
        for (int j = 0; j < 8; j++) Al[chunk * 8 + j] = v[j];
    }
    __syncthreads();
    int w = tid >> 6, l = tid & 63;
    int rt0 = (w & 1) * 4, ct0 = (w >> 1) * 4;
    int lq = l >> 4, ln = l & 15;
    f32x4 acc[4][4];
    for (int i = 0; i < 4; i++)
        for (int j = 0; j < 4; j++)
            for (int r = 0; r < 4; r++) acc[i][j][r] = 0.0f;
    for (int c = 0; c < 4; c++) {
        bf16x8 af[4], bf[4];
        for (int i = 0; i < 4; i++) af[i] = *(const bf16x8*)(Al + (((rt0 + i) * 4 + c) * 64 + l) * 8);
        for (int j = 0; j < 4; j++) bf[j] = *(const bf16x8*)(Wf1 + (size_t)((((ct0 + j) * 4 + c) * 64 + l) * 8));
        for (int i = 0; i < 4; i++)
            for (int j = 0; j < 4; j++)
                acc[i][j] = __builtin_amdgcn_mfma_f32_16x16x32_bf16(af[i], bf[j], acc[i][j], 0, 0, 0);
    }
    __syncthreads();   // all MFMA1 reads of Al done
    // H = relu(C1 + b1) -> Al in A-fragment order:
    for (int j = 0; j < 4; j++) {
        int n = (ct0 + j) * 16 + ln;
        float bv = xv(bias1, n, f32m);
        int c = n >> 5, lo = ((n >> 3) & 3) * 16, j2 = n & 7;
        for (int i = 0; i < 4; i++) {
            int r = rt0 + i;
            for (int rg = 0; rg < 4; rg++) {
                float h = acc[i][j][rg] + bv;
                if (h < 0.0f) h = 0.0f;
                Al[((r * 4 + c) * 64 + lo + lq * 4 + rg) * 8 + j2] = f2b(h);
            }
        }
    }
    __syncthreads();
    for (int i = 0; i < 4; i++)
        for (int j = 0; j < 4; j++)
            for (int r = 0; r < 4; r++) acc[i][j][r] = 0.0f;
    for (int c = 0; c < 4; c++) {
        bf16x8 af[4], bf[4];
        for (int i = 0; i < 4; i++) af[i] = *(const bf16x8*)(Al + (((rt0 + i) * 4 + c) * 64 + l) * 8);
        for (int j = 0; j < 4; j++) bf[j] = *(const bf16x8*)(Wf2 + (size_t)((((ct0 + j) * 4 + c) * 64 + l) * 8));
        for (int i = 0; i < 4; i++)
            for (int j = 0; j < 4; j++)
                acc[i][j] = __builtin_amdgcn_mfma_f32_16x16x32_bf16(af[i], bf[j], acc[i][j], 0, 0, 0);
    }
    __syncthreads();   // before overwriting Al as row-major C2
    for (int j = 0; j < 4; j++) {
        int n = (ct0 + j) * 16 + ln;
        float bv = xv(bias2, n, f32m);
        for (int i = 0; i < 4; i++) {
            int mb = (rt0 + i) * 16 + lq * 4;
            for (int rg = 0; rg < 4; rg++)
                Al[(mb + rg) * 128 + n] = f2b(acc[i][j][rg] + bv);
        }
    }
    __syncthreads();
    // coalesced store: Al row-major == lgX tile layout
    for (int i = 0; i < 8; i++) {
        int idx = i * 256 + tid;
        if (e0 + (idx >> 4) < EE)
            ((uint4*)Out)[(size_t)e0 * 16 + idx] = ((const uint4*)Al)[idx];
    }
}

// out[n] = x[n] + relu(mean over ALL in-edges of lgX[e]) (0 if deg==0).
// One wave per node, lane owns columns 2l,2l+1.
__global__ void LGNNGINELayer_12463995093126_kernel(
    const void* x, const unsigned short* lgX, const int* row_ptr,
    const unsigned* elist, void* out, const int* flg) {
    int n = blockIdx.x * 4 + (threadIdx.x >> 6);
    if (n >= NN) return;
    int l = threadIdx.x & 63, k0 = l * 2;
    int f32m = flg[0];
    int lo = row_ptr[n], hi = row_ptr[n + 1];
    float a0 = 0.0f, a1 = 0.0f;
    for (int p = lo; p < hi; p++) {
        int e = (int)(elist[p] & 0x7fffffffu);
        unsigned u = *(const unsigned*)(lgX + (size_t)e * 128 + k0);
        a0 += b2f((unsigned short)u);
        a1 += b2f((unsigned short)(u >> 16));
    }
    float g0 = 0.0f, g1 = 0.0f;
    if (hi > lo) {
        float inv = 1.0f / (float)(hi - lo);
        g0 = fmaxf(a0 * inv, 0.0f);
        g1 = fmaxf(a1 * inv, 0.0f);
    }
    float r0 = xv(x, (long)n * 128 + k0, f32m) + g0;
    float r1 = xv(x, (long)n * 128 + k0 + 1, f32m) + g1;
    if (f32m) {
        ((float*)out)[(long)n * 128 + k0] = r0;
        ((float*)out)[(long)n * 128 + k0 + 1] = r1;
    } else {
        unsigned o = ((unsigned)f2b(r1) << 16) | (unsigned)f2b(r0);
        *(unsigned*)((unsigned short*)out + (long)n * 128 + k0) = o;
    }
}

extern "C" void kernel_launch(void* const* d_in, const int* in_sizes, int n_in,
                              void* d_out, int out_size, void* d_ws, size_t ws_size,
                              hipStream_t stream) {
    (void)in_sizes; (void)n_in; (void)out_size; (void)ws_size;
    const void* x = d_in[0];
    const void* W1 = d_in[1];
    const void* b1 = d_in[2];
    const void* W2 = d_in[3];
    const void* b2 = d_in[4];
    const int* col0 = (const int*)d_in[5];
    const int* col1 = (const int*)d_in[6];

    // ws: lgX bf16 51.2MB | S bf16 12.8MB | row_ptr | cursor | counts | aux | elist | flg | Wf1 | Wf2
    char* p = (char*)d_ws;
    unsigned short* lgX = (unsigned short*)p; p += (size_t)EE * 128 * 2;
    unsigned short* S = (unsigned short*)p;   p += (size_t)NN * 128 * 2;
    int* row_ptr = (int*)p;                   p += (size_t)(NN + 16) * 4;
    int* cursor = (int*)p;                    p += (size_t)NN * 4;
    int* counts = (int*)p;                    p += (size_t)NN * 4;
    int* aux = (int*)p;                       p += (size_t)EE * 4;
    unsigned* elist = (unsigned*)p;           p += (size_t)EE * 4;
    int* flg = (int*)p;                       p += 256;
    unsigned short* Wf1 = (unsigned short*)p; p += 16384 * 2;
    unsigned short* Wf2 = (unsigned short*)p;

    int gB = (EE + 127) / 128;
    int eB = (EE + 255) / 256;
    int nB4 = (NN + 3) / 4;   // one wave per node, 4 nodes/block

    k_detect<<<1, 64, 0, stream>>>((const unsigned short*)x, col0, flg);
    k_wfrag<<<8, 256, 0, stream>>>(W1, Wf1, flg);
    k_wfrag<<<8, 256, 0, stream>>>(W2, Wf2, flg);

    // CSR by col1 (built once; col1 fixed across iterations)
    k_zero<<<(NN + 255) / 256, 256, 0, stream>>>((unsigned*)counts, NN);
    k_hist<<<eB, 256, 0, stream>>>(col1, counts, flg);
    k_scan<<<1, 1024, 0, stream>>>(counts, row_ptr, cursor);
    k_cscatter<<<eB, 256, 0, stream>>>(col0, col1, cursor, elist, aux, flg);

    // iteration 1: S from x directly (lgX0 never materialized), fused MLP -> lgX1
    k_gath<<<nB4, 256, 0, stream>>>(x, lgX, row_ptr, elist, aux, S, flg, 1);
    k_fused<<<gB, 256, 0, stream>>>(lgX, S, col0, col1, x, Wf1, Wf2, b1, b2,
                                    lgX, flg, 1);
    // iteration 2
    k_gath<<<nB4, 256, 0, stream>>>(x, lgX, row_ptr, elist, aux, S, flg, 2);
    k_fused<<<gB, 256, 0, stream>>>(lgX, S, col0, col1, x, Wf1, Wf2, b1, b2,
                                    lgX, flg, 0);
    // scatter_mean back to nodes (as CSR gather) + residual/relu
    LGNNGINELayer_12463995093126_kernel<<<nB4, 256, 0, stream>>>(
        x, lgX, row_ptr, elist, d_out, flg);
}

// Round 5
// 553.208 us; speedup vs baseline: 1.4254x; 1.1790x over previous
//
#include <hip/hip_runtime.h>
#include <hip/hip_bf16.h>

constexpr int NN = 50000;
constexpr int EE = 200000;
typedef __bf16 bf16x8 __attribute__((ext_vector_type(8)));
typedef float f32x4 __attribute__((ext_vector_type(4)));

__device__ __forceinline__ float b2f(unsigned short s) {
    union { unsigned u; float f; } c; c.u = ((unsigned)s) << 16; return c.f;
}
__device__ __forceinline__ unsigned short f2b(float f) {
    union { float f; unsigned u; } c; c.f = f;
    unsigned u = c.u + 0x7fffu + ((c.u >> 16) & 1u);
    return (unsigned short)(u >> 16);
}
__device__ __forceinline__ float xv(const void* p, long i, int f32m) {
    return f32m ? ((const float*)p)[i] : b2f(((const unsigned short*)p)[i]);
}
__device__ __forceinline__ int iv(const int* p, int i, int i64m) {
    return i64m ? p[2 * i] : p[i];
}

__global__ void k_detect(const unsigned short* x16, const int* c32, int* flg) {
    if (threadIdx.x != 0 || blockIdx.x != 0) return;
    int f32m = 0;
    for (int i = 0; i < 16384; i++)
        if (((x16[i] >> 7) & 0xFF) == 0xFF) { f32m = 1; break; }
    int i64m = 1;
    for (int i = 1; i < 128; i += 2)
        if (c32[i] != 0) { i64m = 0; break; }
    flg[0] = f32m; flg[1] = i64m;
}

__global__ void k_zero(unsigned* p, int n) {
    int i = blockIdx.x * 256 + threadIdx.x;
    if (i < n) p[i] = 0u;
}

// Pack W into bf16 MFMA B-fragment image: chunk=(t*4+c)*64+l ;
// Wf[chunk*8+j] = W[c*32+(l>>4)*8+j][t*16+(l&15)]
__global__ void k_wfrag(const void* W, unsigned short* Wf, const int* flg) {
    int f32m = flg[0];
    int chunk = blockIdx.x * 256 + threadIdx.x;
    if (chunk >= 2048) return;
    int l = chunk & 63, c = (chunk >> 6) & 3, t = chunk >> 8;
    int n = t * 16 + (l & 15), k0 = c * 32 + ((l >> 4) * 8);
    for (int j = 0; j < 8; j++) Wf[chunk * 8 + j] = f2b(xv(W, (long)(k0 + j) * 128 + n, f32m));
}

// ---- CSR build (by col1), done once ----
__global__ void k_hist(const int* col1, int* counts, const int* flg) {
    int e = blockIdx.x * 256 + threadIdx.x;
    if (e >= EE) return;
    atomicAdd(&counts[iv(col1, e, flg[1])], 1);
}

__global__ void k_scan(const int* counts, int* row_ptr, int* cursor) {
    __shared__ int part[1024];
    int t = threadIdx.x;
    const int CH = (NN + 1023) / 1024;
    int base = t * CH;
    int s = 0;
    for (int i = 0; i < CH; i++) { int idx = base + i; if (idx < NN) s += counts[idx]; }
    part[t] = s;
    __syncthreads();
    for (int off = 1; off < 1024; off <<= 1) {
        int v = (t >= off) ? part[t - off] : 0;
        __syncthreads();
        part[t] += v;
        __syncthreads();
    }
    int ex = (t == 0) ? 0 : part[t - 1];
    for (int i = 0; i < CH; i++) {
        int idx = base + i;
        if (idx < NN) { row_ptr[idx] = ex; cursor[idx] = ex; ex += counts[idx]; }
    }
    if (t == 1023) row_ptr[NN] = part[1023];
}

__global__ void k_cscatter(const int* col0, const int* col1, int* cursor,
                           unsigned* elist, int* aux, const int* flg) {
    int e = blockIdx.x * 256 + threadIdx.x;
    if (e >= EE) return;
    int i64m = flg[1];
    int a = iv(col0, e, i64m), b = iv(col1, e, i64m);
    int pos = atomicAdd(&cursor[b], 1);
    elist[pos] = (unsigned)e | (a == b ? 0x80000000u : 0u);
    aux[pos] = a;
}

// S[n][k] (bf16) = sum over non-self-loop in-edges of relu(msg).
//   mode 1: msg = 0.5*x[aux[p]] + 1.5*x[n]   (lgX0 never materialized)
//   mode 2: msg = lgX[e] + x[n]
// One wave per node; lane owns columns 2l,2l+1 (u32 paired-bf16 loads).
__global__ void k_gath(const void* x, const unsigned short* lgX,
                       const int* row_ptr, const unsigned* elist, const int* aux,
                       unsigned short* S, const int* flg, int mode) {
    int n = blockIdx.x * 4 + (threadIdx.x >> 6);
    if (n >= NN) return;
    int l = threadIdx.x & 63, k0 = l * 2;
    int f32m = flg[0];
    int lo = row_ptr[n], hi = row_ptr[n + 1];
    float xn0, xn1;
    if (f32m) {
        xn0 = ((const float*)x)[(size_t)n * 128 + k0];
        xn1 = ((const float*)x)[(size_t)n * 128 + k0 + 1];
    } else {
        unsigned u = *(const unsigned*)((const unsigned short*)x + (size_t)n * 128 + k0);
        xn0 = b2f((unsigned short)u); xn1 = b2f((unsigned short)(u >> 16));
    }
    float a0 = 0.0f, a1 = 0.0f;
    if (mode == 1) {
        if (f32m) {
            for (int p = lo; p < hi; p++) {
                unsigned pk = elist[p];
                if (pk & 0x80000000u) continue;
                const float* xa = (const float*)x + (size_t)aux[p] * 128 + k0;
                a0 += fmaxf(0.5f * xa[0] + 1.5f * xn0, 0.0f);
                a1 += fmaxf(0.5f * xa[1] + 1.5f * xn1, 0.0f);
            }
        } else {
            for (int p = lo; p < hi; p++) {
                unsigned pk = elist[p];
                if (pk & 0x80000000u) continue;
                unsigned u = *(const unsigned*)((const unsigned short*)x + (size_t)aux[p] * 128 + k0);
                a0 += fmaxf(0.5f * b2f((unsigned short)u) + 1.5f * xn0, 0.0f);
                a1 += fmaxf(0.5f * b2f((unsigned short)(u >> 16)) + 1.5f * xn1, 0.0f);
            }
        }
    } else {
        for (int p = lo; p < hi; p++) {
            unsigned pk = elist[p];
            if (pk & 0x80000000u) continue;
            int e = (int)(pk & 0x7fffffffu);
            unsigned u = *(const unsigned*)(lgX + (size_t)e * 128 + k0);
            a0 += fmaxf(b2f((unsigned short)u) + xn0, 0.0f);
            a1 += fmaxf(b2f((unsigned short)(u >> 16)) + xn1, 0.0f);
        }
    }
    unsigned o = ((unsigned)f2b(a1) << 16) | (unsigned)f2b(a0);
    *(unsigned*)(S + (size_t)n * 128 + k0) = o;
}

// Fused 2-layer MLP, BARRIER-FREE: each wave owns 16 edge rows end-to-end.
// Out = (relu((A + S[col0]) @ W1 + b1)) @ W2 + b2, in-place capable.
// Wave-private 4KB LDS region: A-frags -> (GEMM1, B from global Wf1) ->
// H re-laid as A-frags (same region) -> GEMM2 -> C2 row-major -> coalesced store.
// All LDS deps are same-wave (lgkmcnt only); waves drift freely -> latency hiding.
__global__ __launch_bounds__(256, 5)
void k_fused(const unsigned short* A, const unsigned short* S,
             const int* col0in, const int* col1in, const void* x,
             const unsigned short* Wf1, const unsigned short* Wf2,
             const void* bias1, const void* bias2,
             unsigned short* Out, const int* flg, int initA) {
    __shared__ unsigned short Lds[8192];   // 16 KB: 4 waves x 4 KB
    int f32m = flg[0], i64m = flg[1];
    int tid = threadIdx.x;
    int w = tid >> 6, l = tid & 63;
    int lq = l >> 4, ln = l & 15;
    int e0 = blockIdx.x * 64 + w * 16;     // wave's 16 edge rows (EE % 64 == 0)
    unsigned short* W_ = Lds + w * 2048;   // wave-private region

    // ---- stage A-frag: lane l handles row e0+ln, k-group lq*8, over c=0..3
    int row = e0 + ln;
    int aN = iv(col0in, row, i64m);
    int bN = initA ? iv(col1in, row, i64m) : 0;
    for (int c = 0; c < 4; c++) {
        int k0 = c * 32 + lq * 8;
        uint4 svv = *(const uint4*)(S + (size_t)aN * 128 + k0);
        const unsigned short* sp = (const unsigned short*)&svv;
        unsigned short v[8];
        if (initA) {
            if (f32m) {
                const float* xa = (const float*)x + (size_t)aN * 128 + k0;
                const float* xb = (const float*)x + (size_t)bN * 128 + k0;
                for (int j = 0; j < 8; j++)
                    v[j] = f2b(0.5f * (xa[j] + xb[j]) + b2f(sp[j]));
            } else {
                uint4 xav = *(const uint4*)((const unsigned short*)x + (size_t)aN * 128 + k0);
                uint4 xbv = *(const uint4*)((const unsigned short*)x + (size_t)bN * 128 + k0);
                const unsigned short* xa = (const unsigned short*)&xav;
                const unsigned short* xb = (const unsigned short*)&xbv;
                for (int j = 0; j < 8; j++)
                    v[j] = f2b(0.5f * (b2f(xa[j]) + b2f(xb[j])) + b2f(sp[j]));
            }
        } else {
            uint4 av = *(const uint4*)(A + (size_t)row * 128 + k0);
            const unsigned short* ap = (const unsigned short*)&av;
            for (int j = 0; j < 8; j++) v[j] = f2b(b2f(ap[j]) + b2f(sp[j]));
        }
        *(uint4*)(W_ + (c * 64 + l) * 8) = *(const uint4*)v;
    }

    // ---- GEMM1: rows 16, cols 128; A-frag same for all col-tiles
    f32x4 acc[8];
    for (int j = 0; j < 8; j++)
        for (int r = 0; r < 4; r++) acc[j][r] = 0.0f;
    for (int c = 0; c < 4; c++) {
        bf16x8 af = *(const bf16x8*)(W_ + (c * 64 + l) * 8);
        for (int j = 0; j < 8; j++) {
            bf16x8 bf = *(const bf16x8*)(Wf1 + (size_t)(((j * 4 + c) * 64 + l) * 8));
            acc[j] = __builtin_amdgcn_mfma_f32_16x16x32_bf16(af, bf, acc[j], 0, 0, 0);
        }
    }

    // ---- H = relu(C1+b1) -> same region, A-frag order (same-wave dep only)
    // element (m16 = lq*4+rg, n): chunk c2=n>>5, lane (m16)+16*((n>>3)&3), elem n&7
    for (int j = 0; j < 8; j++) {
        int n = j * 16 + ln;
        float bv = xv(bias1, n, f32m);
        int c2 = n >> 5, lhi = ((n >> 3) & 3) * 16, j2 = n & 7;
        for (int rg = 0; rg < 4; rg++) {
            float h = acc[j][rg] + bv;
            if (h < 0.0f) h = 0.0f;
            W_[(c2 * 64 + lhi + lq * 4 + rg) * 8 + j2] = f2b(h);
        }
    }

    // ---- GEMM2
    for (int j = 0; j < 8; j++)
        for (int r = 0; r < 4; r++) acc[j][r] = 0.0f;
    for (int c = 0; c < 4; c++) {
        bf16x8 af = *(const bf16x8*)(W_ + (c * 64 + l) * 8);
        for (int j = 0; j < 8; j++) {
            bf16x8 bf = *(const bf16x8*)(Wf2 + (size_t)(((j * 4 + c) * 64 + l) * 8));
            acc[j] = __builtin_amdgcn_mfma_f32_16x16x32_bf16(af, bf, acc[j], 0, 0, 0);
        }
    }

    // ---- C2 + b2 -> row-major in region, then coalesced uint4 store
    for (int j = 0; j < 8; j++) {
        int n = j * 16 + ln;
        float bv = xv(bias2, n, f32m);
        for (int rg = 0; rg < 4; rg++)
            W_[(lq * 4 + rg) * 128 + n] = f2b(acc[j][rg] + bv);
    }
    for (int i = 0; i < 4; i++) {
        int idx = i * 64 + l;    // 256 uint4 = 16 rows x 256B
        ((uint4*)Out)[(size_t)e0 * 16 + idx] = ((const uint4*)W_)[idx];
    }
}

// out[n] = x[n] + relu(mean over ALL in-edges of lgX[e]) (0 if deg==0).
__global__ void LGNNGINELayer_12463995093126_kernel(
    const void* x, const unsigned short* lgX, const int* row_ptr,
    const unsigned* elist, void* out, const int* flg) {
    int n = blockIdx.x * 4 + (threadIdx.x >> 6);
    if (n >= NN) return;
    int l = threadIdx.x & 63, k0 = l * 2;
    int f32m = flg[0];
    int lo = row_ptr[n], hi = row_ptr[n + 1];
    float a0 = 0.0f, a1 = 0.0f;
    for (int p = lo; p < hi; p++) {
        int e = (int)(elist[p] & 0x7fffffffu);
        unsigned u = *(const unsigned*)(lgX + (size_t)e * 128 + k0);
        a0 += b2f((unsigned short)u);
        a1 += b2f((unsigned short)(u >> 16));
    }
    float g0 = 0.0f, g1 = 0.0f;
    if (hi > lo) {
        float inv = 1.0f / (float)(hi - lo);
        g0 = fmaxf(a0 * inv, 0.0f);
        g1 = fmaxf(a1 * inv, 0.0f);
    }
    if (f32m) {
        ((float*)out)[(long)n * 128 + k0]     = ((const float*)x)[(long)n * 128 + k0] + g0;
        ((float*)out)[(long)n * 128 + k0 + 1] = ((const float*)x)[(long)n * 128 + k0 + 1] + g1;
    } else {
        unsigned u = *(const unsigned*)((const unsigned short*)x + (long)n * 128 + k0);
        float r0 = b2f((unsigned short)u) + g0;
        float r1 = b2f((unsigned short)(u >> 16)) + g1;
        unsigned o = ((unsigned)f2b(r1) << 16) | (unsigned)f2b(r0);
        *(unsigned*)((unsigned short*)out + (long)n * 128 + k0) = o;
    }
}

extern "C" void kernel_launch(void* const* d_in, const int* in_sizes, int n_in,
                              void* d_out, int out_size, void* d_ws, size_t ws_size,
                              hipStream_t stream) {
    (void)in_sizes; (void)n_in; (void)out_size; (void)ws_size;
    const void* x = d_in[0];
    const void* W1 = d_in[1];
    const void* b1 = d_in[2];
    const void* W2 = d_in[3];
    const void* b2 = d_in[4];
    const int* col0 = (const int*)d_in[5];
    const int* col1 = (const int*)d_in[6];

    // ws: lgX bf16 51.2MB | S bf16 12.8MB | row_ptr | cursor | counts | aux | elist | flg | Wf1 | Wf2
    char* p = (char*)d_ws;
    unsigned short* lgX = (unsigned short*)p; p += (size_t)EE * 128 * 2;
    unsigned short* S = (unsigned short*)p;   p += (size_t)NN * 128 * 2;
    int* row_ptr = (int*)p;                   p += (size_t)(NN + 16) * 4;
    int* cursor = (int*)p;                    p += (size_t)NN * 4;
    int* counts = (int*)p;                    p += (size_t)NN * 4;
    int* aux = (int*)p;                       p += (size_t)EE * 4;
    unsigned* elist = (unsigned*)p;           p += (size_t)EE * 4;
    int* flg = (int*)p;                       p += 256;
    unsigned short* Wf1 = (unsigned short*)p; p += 16384 * 2;
    unsigned short* Wf2 = (unsigned short*)p;

    int gB = EE / 64;                 // 3125 blocks, wave = 16 rows, no tail
    int eB = (EE + 255) / 256;
    int nB4 = (NN + 3) / 4;

    k_detect<<<1, 64, 0, stream>>>((const unsigned short*)x, col0, flg);
    k_wfrag<<<8, 256, 0, stream>>>(W1, Wf1, flg);
    k_wfrag<<<8, 256, 0, stream>>>(W2, Wf2, flg);

    // CSR by col1 (col1 fixed across iterations)
    k_zero<<<(NN + 255) / 256, 256, 0, stream>>>((unsigned*)counts, NN);
    k_hist<<<eB, 256, 0, stream>>>(col1, counts, flg);
    k_scan<<<1, 1024, 0, stream>>>(counts, row_ptr, cursor);
    k_cscatter<<<eB, 256, 0, stream>>>(col0, col1, cursor, elist, aux, flg);

    // iteration 1: S from x directly, fused MLP -> lgX1
    k_gath<<<nB4, 256, 0, stream>>>(x, lgX, row_ptr, elist, aux, S, flg, 1);
    k_fused<<<gB, 256, 0, stream>>>(lgX, S, col0, col1, x, Wf1, Wf2, b1, b2,
                                    lgX, flg, 1);
    // iteration 2
    k_gath<<<nB4, 256, 0, stream>>>(x, lgX, row_ptr, elist, aux, S, flg, 2);
    k_fused<<<gB, 256, 0, stream>>>(lgX, S, col0, col1, x, Wf1, Wf2, b1, b2,
                                    lgX, flg, 0);
    // scatter_mean back to nodes (CSR gather) + residual/relu
    LGNNGINELayer_12463995093126_kernel<<<nB4, 256, 0, stream>>>(
        x, lgX, row_ptr, elist, d_out, flg);
}

// Round 6
// 392.495 us; speedup vs baseline: 2.0090x; 1.4095x over previous
//
#include <hip/hip_runtime.h>
#include <hip/hip_bf16.h>

constexpr int NN = 50000;
constexpr int EE = 200000;
typedef __bf16 bf16x8 __attribute__((ext_vector_type(8)));
typedef float f32x4 __attribute__((ext_vector_type(4)));

__device__ __forceinline__ float b2f(unsigned short s) {
    union { unsigned u; float f; } c; c.u = ((unsigned)s) << 16; return c.f;
}
__device__ __forceinline__ unsigned short f2b(float f) {
    union { float f; unsigned u; } c; c.f = f;
    unsigned u = c.u + 0x7fffu + ((c.u >> 16) & 1u);
    return (unsigned short)(u >> 16);
}
__device__ __forceinline__ float xv(const void* p, long i, int f32m) {
    return f32m ? ((const float*)p)[i] : b2f(((const unsigned short*)p)[i]);
}
__device__ __forceinline__ int iv(const int* p, int i, int i64m) {
    return i64m ? p[2 * i] : p[i];
}

// parallel dtype sniff: 256 threads, benign-race shared flags
__global__ void k_detect(const unsigned short* x16, const int* c32, int* flg) {
    __shared__ int sf, si;
    int t = threadIdx.x;
    if (t == 0) { sf = 0; si = 1; }
    __syncthreads();
    for (int i = t; i < 16384; i += 256)
        if (((x16[i] >> 7) & 0xFF) == 0xFF) sf = 1;
    if (t < 64)
        if (c32[2 * t + 1] != 0) si = 0;
    __syncthreads();
    if (t == 0) { flg[0] = sf; flg[1] = si; }
}

__global__ void k_zero(unsigned* p, int n) {
    int i = blockIdx.x * 256 + threadIdx.x;
    if (i < n) p[i] = 0u;
}

// Pack W into bf16 MFMA B-fragment image: chunk=(t*4+c)*64+l ;
// Wf[chunk*8+j] = W[c*32+(l>>4)*8+j][t*16+(l&15)]
__global__ void k_wfrag(const void* W, unsigned short* Wf, const int* flg) {
    int f32m = flg[0];
    int chunk = blockIdx.x * 256 + threadIdx.x;
    if (chunk >= 2048) return;
    int l = chunk & 63, c = (chunk >> 6) & 3, t = chunk >> 8;
    int n = t * 16 + (l & 15), k0 = c * 32 + ((l >> 4) * 8);
    for (int j = 0; j < 8; j++) Wf[chunk * 8 + j] = f2b(xv(W, (long)(k0 + j) * 128 + n, f32m));
}

// ---- CSR build (by col1), done once ----
__global__ void k_hist(const int* col1, int* counts, const int* flg) {
    int e = blockIdx.x * 256 + threadIdx.x;
    if (e >= EE) return;
    atomicAdd(&counts[iv(col1, e, flg[1])], 1);
}

// multi-block scan, stage 1: per-block sums (256 counts/block)
__global__ void k_scan1(const int* counts, int* bsum) {
    __shared__ int sh[256];
    int b = blockIdx.x, t = threadIdx.x;
    int idx = b * 256 + t;
    sh[t] = (idx < NN) ? counts[idx] : 0;
    __syncthreads();
    for (int off = 128; off > 0; off >>= 1) {
        if (t < off) sh[t] += sh[t + off];
        __syncthreads();
    }
    if (t == 0) bsum[b] = sh[0];
}

// stage 2: base = sum(bsum[0..b)) (nb<=256 -> one pass), intra-block exclusive
// scan, write row_ptr & cursor; last element writes row_ptr[NN].
__global__ void k_scan2(const int* counts, const int* bsum,
                        int* row_ptr, int* cursor) {
    __shared__ int sh[256];
    __shared__ int base_s;
    int b = blockIdx.x, t = threadIdx.x;
    sh[t] = (t < b) ? bsum[t] : 0;
    __syncthreads();
    for (int off = 128; off > 0; off >>= 1) {
        if (t < off) sh[t] += sh[t + off];
        __syncthreads();
    }
    if (t == 0) base_s = sh[0];
    __syncthreads();
    int idx = b * 256 + t;
    int v = (idx < NN) ? counts[idx] : 0;
    sh[t] = v;
    __syncthreads();
    for (int off = 1; off < 256; off <<= 1) {
        int add = (t >= off) ? sh[t - off] : 0;
        __syncthreads();
        sh[t] += add;
        __syncthreads();
    }
    int ex = base_s + sh[t] - v;   // exclusive prefix
    if (idx < NN) { row_ptr[idx] = ex; cursor[idx] = ex; }
    if (idx == NN - 1) row_ptr[NN] = ex + v;
}

__global__ void k_cscatter(const int* col0, const int* col1, int* cursor,
                           unsigned* elist, int* aux, const int* flg) {
    int e = blockIdx.x * 256 + threadIdx.x;
    if (e >= EE) return;
    int i64m = flg[1];
    int a = iv(col0, e, i64m), b = iv(col1, e, i64m);
    int pos = atomicAdd(&cursor[b], 1);
    elist[pos] = (unsigned)e | (a == b ? 0x80000000u : 0u);
    aux[pos] = a;
}

// S[n][k] (bf16) = sum over non-self-loop in-edges of relu(msg).
//   mode 1: msg = 0.5*x[aux[p]] + 1.5*x[n]   (lgX0 never materialized)
//   mode 2: msg = lgX[e] + x[n]
// One wave per node; lane owns columns 2l,2l+1 (u32 paired-bf16 loads).
__global__ void k_gath(const void* x, const unsigned short* lgX,
                       const int* row_ptr, const unsigned* elist, const int* aux,
                       unsigned short* S, const int* flg, int mode) {
    int n = blockIdx.x * 4 + (threadIdx.x >> 6);
    if (n >= NN) return;
    int l = threadIdx.x & 63, k0 = l * 2;
    int f32m = flg[0];
    int lo = row_ptr[n], hi = row_ptr[n + 1];
    float xn0, xn1;
    if (f32m) {
        xn0 = ((const float*)x)[(size_t)n * 128 + k0];
        xn1 = ((const float*)x)[(size_t)n * 128 + k0 + 1];
    } else {
        unsigned u = *(const unsigned*)((const unsigned short*)x + (size_t)n * 128 + k0);
        xn0 = b2f((unsigned short)u); xn1 = b2f((unsigned short)(u >> 16));
    }
    float a0 = 0.0f, a1 = 0.0f;
    if (mode == 1) {
        if (f32m) {
            for (int p = lo; p < hi; p++) {
                unsigned pk = elist[p];
                if (pk & 0x80000000u) continue;
                const float* xa = (const float*)x + (size_t)aux[p] * 128 + k0;
                a0 += fmaxf(0.5f * xa[0] + 1.5f * xn0, 0.0f);
                a1 += fmaxf(0.5f * xa[1] + 1.5f * xn1, 0.0f);
            }
        } else {
            for (int p = lo; p < hi; p++) {
                unsigned pk = elist[p];
                if (pk & 0x80000000u) continue;
                unsigned u = *(const unsigned*)((const unsigned short*)x + (size_t)aux[p] * 128 + k0);
                a0 += fmaxf(0.5f * b2f((unsigned short)u) + 1.5f * xn0, 0.0f);
                a1 += fmaxf(0.5f * b2f((unsigned short)(u >> 16)) + 1.5f * xn1, 0.0f);
            }
        }
    } else {
        for (int p = lo; p < hi; p++) {
            unsigned pk = elist[p];
            if (pk & 0x80000000u) continue;
            int e = (int)(pk & 0x7fffffffu);
            unsigned u = *(const unsigned*)(lgX + (size_t)e * 128 + k0);
            a0 += fmaxf(b2f((unsigned short)u) + xn0, 0.0f);
            a1 += fmaxf(b2f((unsigned short)(u >> 16)) + xn1, 0.0f);
        }
    }
    unsigned o = ((unsigned)f2b(a1) << 16) | (unsigned)f2b(a0);
    *(unsigned*)(S + (size_t)n * 128 + k0) = o;
}

// Fused 2-layer MLP, BARRIER-FREE: each wave owns 16 edge rows end-to-end.
// Out = (relu((A + S[col0]) @ W1 + b1)) @ W2 + b2, in-place capable.
// Wave-private 4KB LDS region; all LDS deps same-wave (lgkmcnt only).
__global__ __launch_bounds__(256, 5)
void k_fused(const unsigned short* A, const unsigned short* S,
             const int* col0in, const int* col1in, const void* x,
             const unsigned short* Wf1, const unsigned short* Wf2,
             const void* bias1, const void* bias2,
             unsigned short* Out, const int* flg, int initA) {
    __shared__ unsigned short Lds[8192];   // 16 KB: 4 waves x 4 KB
    int f32m = flg[0], i64m = flg[1];
    int tid = threadIdx.x;
    int w = tid >> 6, l = tid & 63;
    int lq = l >> 4, ln = l & 15;
    int e0 = blockIdx.x * 64 + w * 16;     // wave's 16 edge rows (EE % 64 == 0)
    unsigned short* W_ = Lds + w * 2048;   // wave-private region

    // ---- stage A-frag: lane l handles row e0+ln, k-group lq*8, over c=0..3
    int row = e0 + ln;
    int aN = iv(col0in, row, i64m);
    int bN = initA ? iv(col1in, row, i64m) : 0;
    for (int c = 0; c < 4; c++) {
        int k0 = c * 32 + lq * 8;
        uint4 svv = *(const uint4*)(S + (size_t)aN * 128 + k0);
        const unsigned short* sp = (const unsigned short*)&svv;
        unsigned short v[8];
        if (initA) {
            if (f32m) {
                const float* xa = (const float*)x + (size_t)aN * 128 + k0;
                const float* xb = (const float*)x + (size_t)bN * 128 + k0;
                for (int j = 0; j < 8; j++)
                    v[j] = f2b(0.5f * (xa[j] + xb[j]) + b2f(sp[j]));
            } else {
                uint4 xav = *(const uint4*)((const unsigned short*)x + (size_t)aN * 128 + k0);
                uint4 xbv = *(const uint4*)((const unsigned short*)x + (size_t)bN * 128 + k0);
                const unsigned short* xa = (const unsigned short*)&xav;
                const unsigned short* xb = (const unsigned short*)&xbv;
                for (int j = 0; j < 8; j++)
                    v[j] = f2b(0.5f * (b2f(xa[j]) + b2f(xb[j])) + b2f(sp[j]));
            }
        } else {
            uint4 av = *(const uint4*)(A + (size_t)row * 128 + k0);
            const unsigned short* ap = (const unsigned short*)&av;
            for (int j = 0; j < 8; j++) v[j] = f2b(b2f(ap[j]) + b2f(sp[j]));
        }
        *(uint4*)(W_ + (c * 64 + l) * 8) = *(const uint4*)v;
    }

    // ---- GEMM1: rows 16, cols 128; A-frag same for all col-tiles
    f32x4 acc[8];
    for (int j = 0; j < 8; j++)
        for (int r = 0; r < 4; r++) acc[j][r] = 0.0f;
    for (int c = 0; c < 4; c++) {
        bf16x8 af = *(const bf16x8*)(W_ + (c * 64 + l) * 8);
        for (int j = 0; j < 8; j++) {
            bf16x8 bf = *(const bf16x8*)(Wf1 + (size_t)(((j * 4 + c) * 64 + l) * 8));
            acc[j] = __builtin_amdgcn_mfma_f32_16x16x32_bf16(af, bf, acc[j], 0, 0, 0);
        }
    }

    // ---- H = relu(C1+b1) -> same region, A-frag order (same-wave dep only)
    for (int j = 0; j < 8; j++) {
        int n = j * 16 + ln;
        float bv = xv(bias1, n, f32m);
        int c2 = n >> 5, lhi = ((n >> 3) & 3) * 16, j2 = n & 7;
        for (int rg = 0; rg < 4; rg++) {
            float h = acc[j][rg] + bv;
            if (h < 0.0f) h = 0.0f;
            W_[(c2 * 64 + lhi + lq * 4 + rg) * 8 + j2] = f2b(h);
        }
    }

    // ---- GEMM2
    for (int j = 0; j < 8; j++)
        for (int r = 0; r < 4; r++) acc[j][r] = 0.0f;
    for (int c = 0; c < 4; c++) {
        bf16x8 af = *(const bf16x8*)(W_ + (c * 64 + l) * 8);
        for (int j = 0; j < 8; j++) {
            bf16x8 bf = *(const bf16x8*)(Wf2 + (size_t)(((j * 4 + c) * 64 + l) * 8));
            acc[j] = __builtin_amdgcn_mfma_f32_16x16x32_bf16(af, bf, acc[j], 0, 0, 0);
        }
    }

    // ---- C2 + b2 -> row-major in region, then coalesced uint4 store
    for (int j = 0; j < 8; j++) {
        int n = j * 16 + ln;
        float bv = xv(bias2, n, f32m);
        for (int rg = 0; rg < 4; rg++)
            W_[(lq * 4 + rg) * 128 + n] = f2b(acc[j][rg] + bv);
    }
    for (int i = 0; i < 4; i++) {
        int idx = i * 64 + l;    // 256 uint4 = 16 rows x 256B
        ((uint4*)Out)[(size_t)e0 * 16 + idx] = ((const uint4*)W_)[idx];
    }
}

// out[n] = x[n] + relu(mean over ALL in-edges of lgX[e]) (0 if deg==0).
__global__ void LGNNGINELayer_12463995093126_kernel(
    const void* x, const unsigned short* lgX, const int* row_ptr,
    const unsigned* elist, void* out, const int* flg) {
    int n = blockIdx.x * 4 + (threadIdx.x >> 6);
    if (n >= NN) return;
    int l = threadIdx.x & 63, k0 = l * 2;
    int f32m = flg[0];
    int lo = row_ptr[n], hi = row_ptr[n + 1];
    float a0 = 0.0f, a1 = 0.0f;
    for (int p = lo; p < hi; p++) {
        int e = (int)(elist[p] & 0x7fffffffu);
        unsigned u = *(const unsigned*)(lgX + (size_t)e * 128 + k0);
        a0 += b2f((unsigned short)u);
        a1 += b2f((unsigned short)(u >> 16));
    }
    float g0 = 0.0f, g1 = 0.0f;
    if (hi > lo) {
        float inv = 1.0f / (float)(hi - lo);
        g0 = fmaxf(a0 * inv, 0.0f);
        g1 = fmaxf(a1 * inv, 0.0f);
    }
    if (f32m) {
        ((float*)out)[(long)n * 128 + k0]     = ((const float*)x)[(long)n * 128 + k0] + g0;
        ((float*)out)[(long)n * 128 + k0 + 1] = ((const float*)x)[(long)n * 128 + k0 + 1] + g1;
    } else {
        unsigned u = *(const unsigned*)((const unsigned short*)x + (long)n * 128 + k0);
        float r0 = b2f((unsigned short)u) + g0;
        float r1 = b2f((unsigned short)(u >> 16)) + g1;
        unsigned o = ((unsigned)f2b(r1) << 16) | (unsigned)f2b(r0);
        *(unsigned*)((unsigned short*)out + (long)n * 128 + k0) = o;
    }
}

extern "C" void kernel_launch(void* const* d_in, const int* in_sizes, int n_in,
                              void* d_out, int out_size, void* d_ws, size_t ws_size,
                              hipStream_t stream) {
    (void)in_sizes; (void)n_in; (void)out_size; (void)ws_size;
    const void* x = d_in[0];
    const void* W1 = d_in[1];
    const void* b1 = d_in[2];
    const void* W2 = d_in[3];
    const void* b2 = d_in[4];
    const int* col0 = (const int*)d_in[5];
    const int* col1 = (const int*)d_in[6];

    // ws: lgX | S | row_ptr | cursor | counts | bsum | aux | elist | flg | Wf1 | Wf2
    char* p = (char*)d_ws;
    unsigned short* lgX = (unsigned short*)p; p += (size_t)EE * 128 * 2;
    unsigned short* S = (unsigned short*)p;   p += (size_t)NN * 128 * 2;
    int* row_ptr = (int*)p;                   p += (size_t)(NN + 16) * 4;
    int* cursor = (int*)p;                    p += (size_t)NN * 4;
    int* counts = (int*)p;                    p += (size_t)NN * 4;
    int* bsum = (int*)p;                      p += 256 * 4;
    int* aux = (int*)p;                       p += (size_t)EE * 4;
    unsigned* elist = (unsigned*)p;           p += (size_t)EE * 4;
    int* flg = (int*)p;                       p += 256;
    unsigned short* Wf1 = (unsigned short*)p; p += 16384 * 2;
    unsigned short* Wf2 = (unsigned short*)p;

    int gB = EE / 64;                  // 3125 blocks, wave = 16 rows, no tail
    int eB = (EE + 255) / 256;
    int nB4 = (NN + 3) / 4;
    int sB = (NN + 255) / 256;         // 196 scan blocks

    k_detect<<<1, 256, 0, stream>>>((const unsigned short*)x, col0, flg);
    k_wfrag<<<8, 256, 0, stream>>>(W1, Wf1, flg);
    k_wfrag<<<8, 256, 0, stream>>>(W2, Wf2, flg);

    // CSR by col1 (col1 fixed across iterations)
    k_zero<<<(NN + 255) / 256, 256, 0, stream>>>((unsigned*)counts, NN);
    k_hist<<<eB, 256, 0, stream>>>(col1, counts, flg);
    k_scan1<<<sB, 256, 0, stream>>>(counts, bsum);
    k_scan2<<<sB, 256, 0, stream>>>(counts, bsum, row_ptr, cursor);
    k_cscatter<<<eB, 256, 0, stream>>>(col0, col1, cursor, elist, aux, flg);

    // iteration 1: S from x directly, fused MLP -> lgX1
    k_gath<<<nB4, 256, 0, stream>>>(x, lgX, row_ptr, elist, aux, S, flg, 1);
    k_fused<<<gB, 256, 0, stream>>>(lgX, S, col0, col1, x, Wf1, Wf2, b1, b2,
                                    lgX, flg, 1);
    // iteration 2
    k_gath<<<nB4, 256, 0, stream>>>(x, lgX, row_ptr, elist, aux, S, flg, 2);
    k_fused<<<gB, 256, 0, stream>>>(lgX, S, col0, col1, x, Wf1, Wf2, b1, b2,
                                    lgX, flg, 0);
    // scatter_mean back to nodes (CSR gather) + residual/relu
    LGNNGINELayer_12463995093126_kernel<<<nB4, 256, 0, stream>>>(
        x, lgX, row_ptr, elist, d_out, flg);
}

// Round 7
// 379.727 us; speedup vs baseline: 2.0766x; 1.0336x over previous
//
#include <hip/hip_runtime.h>
#include <hip/hip_bf16.h>

constexpr int NN = 50000;
constexpr int EE = 200000;
typedef __bf16 bf16x8 __attribute__((ext_vector_type(8)));
typedef float f32x4 __attribute__((ext_vector_type(4)));

__device__ __forceinline__ float b2f(unsigned short s) {
    union { unsigned u; float f; } c; c.u = ((unsigned)s) << 16; return c.f;
}
__device__ __forceinline__ unsigned short f2b(float f) {
    union { float f; unsigned u; } c; c.f = f;
    unsigned u = c.u + 0x7fffu + ((c.u >> 16) & 1u);
    return (unsigned short)(u >> 16);
}
__device__ __forceinline__ float xv(const void* p, long i, int f32m) {
    return f32m ? ((const float*)p)[i] : b2f(((const unsigned short*)p)[i]);
}
__device__ __forceinline__ int iv(const int* p, int i, int i64m) {
    return i64m ? p[2 * i] : p[i];
}

// parallel dtype sniff: 256 threads, benign-race shared flags
__global__ void k_detect(const unsigned short* x16, const int* c32, int* flg) {
    __shared__ int sf, si;
    int t = threadIdx.x;
    if (t == 0) { sf = 0; si = 1; }
    __syncthreads();
    for (int i = t; i < 16384; i += 256)
        if (((x16[i] >> 7) & 0xFF) == 0xFF) sf = 1;
    if (t < 64)
        if (c32[2 * t + 1] != 0) si = 0;
    __syncthreads();
    if (t == 0) { flg[0] = sf; flg[1] = si; }
}

__global__ void k_zero(unsigned* p, int n) {
    int i = blockIdx.x * 256 + threadIdx.x;
    if (i < n) p[i] = 0u;
}

// Pack W into bf16 MFMA B-fragment image: chunk=(t*4+c)*64+l ;
// Wf[chunk*8+j] = W[c*32+(l>>4)*8+j][t*16+(l&15)]
__global__ void k_wfrag(const void* W, unsigned short* Wf, const int* flg) {
    int f32m = flg[0];
    int chunk = blockIdx.x * 256 + threadIdx.x;
    if (chunk >= 2048) return;
    int l = chunk & 63, c = (chunk >> 6) & 3, t = chunk >> 8;
    int n = t * 16 + (l & 15), k0 = c * 32 + ((l >> 4) * 8);
    for (int j = 0; j < 8; j++) Wf[chunk * 8 + j] = f2b(xv(W, (long)(k0 + j) * 128 + n, f32m));
}

// ---- CSR build (by col1), done once ----
__global__ void k_hist(const int* col1, int* counts, const int* flg) {
    int e = blockIdx.x * 256 + threadIdx.x;
    if (e >= EE) return;
    atomicAdd(&counts[iv(col1, e, flg[1])], 1);
}

// multi-block scan, stage 1: per-block sums (256 counts/block)
__global__ void k_scan1(const int* counts, int* bsum) {
    __shared__ int sh[256];
    int b = blockIdx.x, t = threadIdx.x;
    int idx = b * 256 + t;
    sh[t] = (idx < NN) ? counts[idx] : 0;
    __syncthreads();
    for (int off = 128; off > 0; off >>= 1) {
        if (t < off) sh[t] += sh[t + off];
        __syncthreads();
    }
    if (t == 0) bsum[b] = sh[0];
}

// stage 2: base = sum(bsum[0..b)), intra-block exclusive scan -> row_ptr/cursor
__global__ void k_scan2(const int* counts, const int* bsum,
                        int* row_ptr, int* cursor) {
    __shared__ int sh[256];
    __shared__ int base_s;
    int b = blockIdx.x, t = threadIdx.x;
    sh[t] = (t < b) ? bsum[t] : 0;
    __syncthreads();
    for (int off = 128; off > 0; off >>= 1) {
        if (t < off) sh[t] += sh[t + off];
        __syncthreads();
    }
    if (t == 0) base_s = sh[0];
    __syncthreads();
    int idx = b * 256 + t;
    int v = (idx < NN) ? counts[idx] : 0;
    sh[t] = v;
    __syncthreads();
    for (int off = 1; off < 256; off <<= 1) {
        int add = (t >= off) ? sh[t - off] : 0;
        __syncthreads();
        sh[t] += add;
        __syncthreads();
    }
    int ex = base_s + sh[t] - v;   // exclusive prefix
    if (idx < NN) { row_ptr[idx] = ex; cursor[idx] = ex; }
    if (idx == NN - 1) row_ptr[NN] = ex + v;
}

// position p (CSR slot under col1): aux[p] = col0[e] | selfloop<<31; node1[p] = col1[e].
// lgX is stored PERMUTED: edge e's features live at row p. elist is not needed.
__global__ void k_cscatter(const int* col0, const int* col1, int* cursor,
                           unsigned* aux, int* node1, const int* flg) {
    int e = blockIdx.x * 256 + threadIdx.x;
    if (e >= EE) return;
    int i64m = flg[1];
    int a = iv(col0, e, i64m), b = iv(col1, e, i64m);
    int pos = atomicAdd(&cursor[b], 1);
    aux[pos] = (unsigned)a | (a == b ? 0x80000000u : 0u);
    node1[pos] = b;
}

// S[n][k] (bf16) = sum over non-self-loop in-edges of relu(msg).
//   mode 1: msg = 0.5*x[col0] + 1.5*x[n]   (lgX0 never materialized; x gather)
//   mode 2: msg = lgX[p] + x[n]            (SEQUENTIAL rows lo..hi)
// One wave per node; lane owns columns 2l,2l+1.
__global__ void k_gath(const void* x, const unsigned short* lgX,
                       const int* row_ptr, const unsigned* aux,
                       unsigned short* S, const int* flg, int mode) {
    int n = blockIdx.x * 4 + (threadIdx.x >> 6);
    if (n >= NN) return;
    int l = threadIdx.x & 63, k0 = l * 2;
    int f32m = flg[0];
    int lo = row_ptr[n], hi = row_ptr[n + 1];
    float xn0, xn1;
    if (f32m) {
        xn0 = ((const float*)x)[(size_t)n * 128 + k0];
        xn1 = ((const float*)x)[(size_t)n * 128 + k0 + 1];
    } else {
        unsigned u = *(const unsigned*)((const unsigned short*)x + (size_t)n * 128 + k0);
        xn0 = b2f((unsigned short)u); xn1 = b2f((unsigned short)(u >> 16));
    }
    float a0 = 0.0f, a1 = 0.0f;
    if (mode == 1) {
        if (f32m) {
            for (int p = lo; p < hi; p++) {
                unsigned av = aux[p];
                if (av & 0x80000000u) continue;
                const float* xa = (const float*)x + (size_t)av * 128 + k0;
                a0 += fmaxf(0.5f * xa[0] + 1.5f * xn0, 0.0f);
                a1 += fmaxf(0.5f * xa[1] + 1.5f * xn1, 0.0f);
            }
        } else {
            for (int p = lo; p < hi; p++) {
                unsigned av = aux[p];
                if (av & 0x80000000u) continue;
                unsigned u = *(const unsigned*)((const unsigned short*)x + (size_t)av * 128 + k0);
                a0 += fmaxf(0.5f * b2f((unsigned short)u) + 1.5f * xn0, 0.0f);
                a1 += fmaxf(0.5f * b2f((unsigned short)(u >> 16)) + 1.5f * xn1, 0.0f);
            }
        }
    } else {
        for (int p = lo; p < hi; p++) {
            if (aux[p] & 0x80000000u) continue;
            unsigned u = *(const unsigned*)(lgX + (size_t)p * 128 + k0);   // sequential
            a0 += fmaxf(b2f((unsigned short)u) + xn0, 0.0f);
            a1 += fmaxf(b2f((unsigned short)(u >> 16)) + xn1, 0.0f);
        }
    }
    unsigned o = ((unsigned)f2b(a1) << 16) | (unsigned)f2b(a0);
    *(unsigned*)(S + (size_t)n * 128 + k0) = o;
}

// Fused 2-layer MLP, BARRIER-FREE: each wave owns 16 CSR positions end-to-end.
// Out = (relu((A + S[col0]) @ W1 + b1)) @ W2 + b2, in-place on permuted lgX.
// Wave-private 4KB LDS region; all LDS deps same-wave (lgkmcnt only).
__global__ __launch_bounds__(256, 8)
void k_fused(const unsigned short* A, const unsigned short* S,
             const unsigned* aux, const int* node1, const void* x,
             const unsigned short* Wf1, const unsigned short* Wf2,
             const void* bias1, const void* bias2,
             unsigned short* Out, const int* flg, int initA) {
    __shared__ unsigned short Lds[8192];   // 16 KB: 4 waves x 4 KB
    int f32m = flg[0];
    int tid = threadIdx.x;
    int w = tid >> 6, l = tid & 63;
    int lq = l >> 4, ln = l & 15;
    int e0 = blockIdx.x * 64 + w * 16;     // wave's 16 positions (EE % 64 == 0)
    unsigned short* W_ = Lds + w * 2048;   // wave-private region

    // ---- stage A-frag: lane l handles position e0+ln, k-group lq*8, c=0..3
    int row = e0 + ln;
    int aN = (int)(aux[row] & 0x7fffffffu);
    int bN = initA ? node1[row] : 0;
    for (int c = 0; c < 4; c++) {
        int k0 = c * 32 + lq * 8;
        uint4 svv = *(const uint4*)(S + (size_t)aN * 128 + k0);
        const unsigned short* sp = (const unsigned short*)&svv;
        unsigned short v[8];
        if (initA) {
            if (f32m) {
                const float* xa = (const float*)x + (size_t)aN * 128 + k0;
                const float* xb = (const float*)x + (size_t)bN * 128 + k0;
                for (int j = 0; j < 8; j++)
                    v[j] = f2b(0.5f * (xa[j] + xb[j]) + b2f(sp[j]));
            } else {
                uint4 xav = *(const uint4*)((const unsigned short*)x + (size_t)aN * 128 + k0);
                uint4 xbv = *(const uint4*)((const unsigned short*)x + (size_t)bN * 128 + k0);
                const unsigned short* xa = (const unsigned short*)&xav;
                const unsigned short* xb = (const unsigned short*)&xbv;
                for (int j = 0; j < 8; j++)
                    v[j] = f2b(0.5f * (b2f(xa[j]) + b2f(xb[j])) + b2f(sp[j]));
            }
        } else {
            uint4 av = *(const uint4*)(A + (size_t)row * 128 + k0);
            const unsigned short* ap = (const unsigned short*)&av;
            for (int j = 0; j < 8; j++) v[j] = f2b(b2f(ap[j]) + b2f(sp[j]));
        }
        *(uint4*)(W_ + (c * 64 + l) * 8) = *(const uint4*)v;
    }

    // ---- GEMM1: rows 16, cols 128
    f32x4 acc[8];
    for (int j = 0; j < 8; j++)
        for (int r = 0; r < 4; r++) acc[j][r] = 0.0f;
    for (int c = 0; c < 4; c++) {
        bf16x8 af = *(const bf16x8*)(W_ + (c * 64 + l) * 8);
        for (int j = 0; j < 8; j++) {
            bf16x8 bf = *(const bf16x8*)(Wf1 + (size_t)(((j * 4 + c) * 64 + l) * 8));
            acc[j] = __builtin_amdgcn_mfma_f32_16x16x32_bf16(af, bf, acc[j], 0, 0, 0);
        }
    }

    // ---- H = relu(C1+b1) -> same region, A-frag order (same-wave dep only)
    for (int j = 0; j < 8; j++) {
        int n = j * 16 + ln;
        float bv = xv(bias1, n, f32m);
        int c2 = n >> 5, lhi = ((n >> 3) & 3) * 16, j2 = n & 7;
        for (int rg = 0; rg < 4; rg++) {
            float h = acc[j][rg] + bv;
            if (h < 0.0f) h = 0.0f;
            W_[(c2 * 64 + lhi + lq * 4 + rg) * 8 + j2] = f2b(h);
        }
    }

    // ---- GEMM2
    for (int j = 0; j < 8; j++)
        for (int r = 0; r < 4; r++) acc[j][r] = 0.0f;
    for (int c = 0; c < 4; c++) {
        bf16x8 af = *(const bf16x8*)(W_ + (c * 64 + l) * 8);
        for (int j = 0; j < 8; j++) {
            bf16x8 bf = *(const bf16x8*)(Wf2 + (size_t)(((j * 4 + c) * 64 + l) * 8));
            acc[j] = __builtin_amdgcn_mfma_f32_16x16x32_bf16(af, bf, acc[j], 0, 0, 0);
        }
    }

    // ---- C2 + b2 -> row-major in region, then coalesced uint4 store
    for (int j = 0; j < 8; j++) {
        int n = j * 16 + ln;
        float bv = xv(bias2, n, f32m);
        for (int rg = 0; rg < 4; rg++)
            W_[(lq * 4 + rg) * 128 + n] = f2b(acc[j][rg] + bv);
    }
    for (int i = 0; i < 4; i++) {
        int idx = i * 64 + l;    // 256 uint4 = 16 rows x 256B
        ((uint4*)Out)[(size_t)e0 * 16 + idx] = ((const uint4*)W_)[idx];
    }
}

// out[n] = x[n] + relu(mean over ALL in-edges of lgX rows lo..hi) (0 if deg==0).
// Fully sequential reads — no index list needed (lgX is CSR-permuted).
__global__ void LGNNGINELayer_12463995093126_kernel(
    const void* x, const unsigned short* lgX, const int* row_ptr,
    void* out, const int* flg) {
    int n = blockIdx.x * 4 + (threadIdx.x >> 6);
    if (n >= NN) return;
    int l = threadIdx.x & 63, k0 = l * 2;
    int f32m = flg[0];
    int lo = row_ptr[n], hi = row_ptr[n + 1];
    float a0 = 0.0f, a1 = 0.0f;
    for (int p = lo; p < hi; p++) {
        unsigned u = *(const unsigned*)(lgX + (size_t)p * 128 + k0);
        a0 += b2f((unsigned short)u);
        a1 += b2f((unsigned short)(u >> 16));
    }
    float g0 = 0.0f, g1 = 0.0f;
    if (hi > lo) {
        float inv = 1.0f / (float)(hi - lo);
        g0 = fmaxf(a0 * inv, 0.0f);
        g1 = fmaxf(a1 * inv, 0.0f);
    }
    if (f32m) {
        ((float*)out)[(long)n * 128 + k0]     = ((const float*)x)[(long)n * 128 + k0] + g0;
        ((float*)out)[(long)n * 128 + k0 + 1] = ((const float*)x)[(long)n * 128 + k0 + 1] + g1;
    } else {
        unsigned u = *(const unsigned*)((const unsigned short*)x + (long)n * 128 + k0);
        float r0 = b2f((unsigned short)u) + g0;
        float r1 = b2f((unsigned short)(u >> 16)) + g1;
        unsigned o = ((unsigned)f2b(r1) << 16) | (unsigned)f2b(r0);
        *(unsigned*)((unsigned short*)out + (long)n * 128 + k0) = o;
    }
}

extern "C" void kernel_launch(void* const* d_in, const int* in_sizes, int n_in,
                              void* d_out, int out_size, void* d_ws, size_t ws_size,
                              hipStream_t stream) {
    (void)in_sizes; (void)n_in; (void)out_size; (void)ws_size;
    const void* x = d_in[0];
    const void* W1 = d_in[1];
    const void* b1 = d_in[2];
    const void* W2 = d_in[3];
    const void* b2 = d_in[4];
    const int* col0 = (const int*)d_in[5];
    const int* col1 = (const int*)d_in[6];

    // ws: lgX(csr) | S | row_ptr | cursor | counts | bsum | aux | node1 | flg | Wf1 | Wf2
    char* p = (char*)d_ws;
    unsigned short* lgX = (unsigned short*)p; p += (size_t)EE * 128 * 2;
    unsigned short* S = (unsigned short*)p;   p += (size_t)NN * 128 * 2;
    int* row_ptr = (int*)p;                   p += (size_t)(NN + 16) * 4;
    int* cursor = (int*)p;                    p += (size_t)NN * 4;
    int* counts = (int*)p;                    p += (size_t)NN * 4;
    int* bsum = (int*)p;                      p += 256 * 4;
    unsigned* aux = (unsigned*)p;             p += (size_t)EE * 4;
    int* node1 = (int*)p;                     p += (size_t)EE * 4;
    int* flg = (int*)p;                       p += 256;
    unsigned short* Wf1 = (unsigned short*)p; p += 16384 * 2;
    unsigned short* Wf2 = (unsigned short*)p;

    int gB = EE / 64;                  // 3125 blocks, wave = 16 positions
    int eB = (EE + 255) / 256;
    int nB4 = (NN + 3) / 4;
    int sB = (NN + 255) / 256;         // 196 scan blocks

    k_detect<<<1, 256, 0, stream>>>((const unsigned short*)x, col0, flg);
    k_wfrag<<<8, 256, 0, stream>>>(W1, Wf1, flg);
    k_wfrag<<<8, 256, 0, stream>>>(W2, Wf2, flg);

    // CSR by col1 (col1 fixed across iterations)
    k_zero<<<(NN + 255) / 256, 256, 0, stream>>>((unsigned*)counts, NN);
    k_hist<<<eB, 256, 0, stream>>>(col1, counts, flg);
    k_scan1<<<sB, 256, 0, stream>>>(counts, bsum);
    k_scan2<<<sB, 256, 0, stream>>>(counts, bsum, row_ptr, cursor);
    k_cscatter<<<eB, 256, 0, stream>>>(col0, col1, cursor, aux, node1, flg);

    // iteration 1: S from x directly, fused MLP -> lgX (CSR-permuted)
    k_gath<<<nB4, 256, 0, stream>>>(x, lgX, row_ptr, aux, S, flg, 1);
    k_fused<<<gB, 256, 0, stream>>>(lgX, S, aux, node1, x, Wf1, Wf2, b1, b2,
                                    lgX, flg, 1);
    // iteration 2 (lgX reads now sequential in k_gath)
    k_gath<<<nB4, 256, 0, stream>>>(x, lgX, row_ptr, aux, S, flg, 2);
    k_fused<<<gB, 256, 0, stream>>>(lgX, S, aux, node1, x, Wf1, Wf2, b1, b2,
                                    lgX, flg, 0);
    // scatter_mean back to nodes (sequential CSR read) + residual/relu
    LGNNGINELayer_12463995093126_kernel<<<nB4, 256, 0, stream>>>(
        x, lgX, row_ptr, d_out, flg);
}